// Round 6
// baseline (1066.053 us; speedup 1.0000x reference)
//
#include <hip/hip_runtime.h>
#include <hip/hip_cooperative_groups.h>
#include <math.h>

namespace cg = cooperative_groups;

#define NN 10000
#define NE 160000
#define NB 128
#define NH 4
#define DOUT 512
#define NEG 0.2f
#define CNT_BLKS ((NE + 255) / 256)    // 625
#define GBM 64
#define GBN 128
#define GBK 64

// shared-memory union carve (bytes)
#define SM_ASH  0        // 8192
#define SM_ASL  8192     // 8192
#define SM_BSH  16384    // 16384
#define SM_BSL  32768    // 16384
#define SM_SRED 49152    // 2048
#define SMEM_SZ 51200
// scan carve
#define SC_SH   0        // 40000
#define SC_PREF 40000    // 1024
#define SC_HIST 41024    // 2048
#define SC_HTMP 43072    // 2048
#define SCAN_SZ 45120
// pool carve
#define PL_RED  0        // 1024
#define PL_COMB 1024     // 12288
#define POOL_SZ 13312

typedef __attribute__((ext_vector_type(8))) short short8;
typedef __attribute__((ext_vector_type(4))) float f32x4;
typedef __attribute__((ext_vector_type(4))) unsigned short us4;

__device__ __forceinline__ float leakyf(float v){ return fmaxf(v, NEG*v); }
__device__ __forceinline__ void fma4(float4& a, const float4 v, float w){
  a.x += v.x*w; a.y += v.y*w; a.z += v.z*w; a.w += v.w*w;
}
__device__ __forceinline__ unsigned short f2bf(float f){
  unsigned int u = __float_as_uint(f);
  u += 0x7FFFu + ((u >> 16) & 1u);
  return (unsigned short)(u >> 16);
}
__device__ __forceinline__ float bf2f(unsigned short h){
  return __uint_as_float(((unsigned int)h) << 16);
}
__device__ __forceinline__ void split2(float v, unsigned short& h, unsigned short& l){
  h = f2bf(v);
  l = f2bf(v - bf2f(h));
}
__device__ __forceinline__ void store_hl(unsigned short* H, unsigned short* L,
                                         size_t base, float4 v){
  us4 h, l; unsigned short hh, ll;
  split2(v.x, hh, ll); h[0]=hh; l[0]=ll;
  split2(v.y, hh, ll); h[1]=hh; l[1]=ll;
  split2(v.z, hh, ll); h[2]=hh; l[2]=ll;
  split2(v.w, hh, ll); h[3]=hh; l[3]=ll;
  *(us4*)&H[base] = h;
  *(us4*)&L[base] = l;
}
__device__ __forceinline__ void gl_lds16(const unsigned short* g, unsigned short* l){
  __builtin_amdgcn_global_load_lds(
      (const __attribute__((address_space(1))) unsigned int*)g,
      (__attribute__((address_space(3))) unsigned int*)l, 16, 0, 0);
}

// ============================ args ============================
struct MegaArgs {
  const float* x0; const int* src; const int* dst; const int* batch;
  int* cnt; int* rowptr; int* colidx; int* cursor; int* starts; int* perm;
  float* dinv; float* apre; float* as_; float* ad_;
  float* f1; float* hf; float* xf;
  unsigned short *actH0,*actL0,*actH1,*actL1,*preH,*preL;
  const unsigned short* wTh[7]; const unsigned short* wTl[7];
  const float* wsrc[7]; unsigned short* wdh[7]; unsigned short* wdl[7];
  int wK[7], wM[7], wKp[7], wTot[7]; int convTot;
  const float* gb[3]; const float* asw[3]; const float* adw[3]; const float* ab[3];
  const float* apb1; const float* apw2v;
  float* out;
};

// ============================ device bodies ============================
__device__ __forceinline__ void dev_conv(const MegaArgs& A, int idx){
  int j = 0;
  while (idx >= A.wTot[j]){ idx -= A.wTot[j]; j++; }
  int Kp = A.wKp[j], K = A.wK[j], M = A.wM[j];
  int kk = idx % Kp, m = idx / Kp;
  float v = (kk < K) ? A.wsrc[j][(size_t)kk*M + m] : 0.f;
  unsigned short h, l; split2(v, h, l);
  A.wdh[j][idx] = h; A.wdl[j][idx] = l;
}

__device__ __forceinline__ void dev_fill(const MegaArgs& A, int e){
  int d = A.dst[e];
  int pos = atomicAdd(&A.cursor[d], 1);
  A.colidx[A.rowptr[d] + pos] = A.src[e];
}

__device__ void dev_scan256(const MegaArgs& A, char* smem){
  int* sh   = (int*)(smem + SC_SH);
  int* pref = (int*)(smem + SC_PREF);
  int* hist = (int*)(smem + SC_HIST);
  int* htmp = (int*)(smem + SC_HTMP);
  int t = threadIdx.x;
  for (int i = t; i < NN; i += 256) sh[i] = A.cnt[i];
  hist[t] = 0; hist[256 + t] = 0;
  if (t <= NB){
    int lo = 0, hi = NN;
    while (lo < hi){ int mid = (lo + hi) >> 1; if (A.batch[mid] < t) lo = mid + 1; else hi = mid; }
    A.starts[t] = lo;
  }
  __syncthreads();
  const int PER = 40;                    // 256*40 >= NN
  int base = t*PER, csum = 0;
  for (int k = 0; k < PER; k++){
    int i = base + k;
    if (i < NN){ csum += sh[i]; atomicAdd(&hist[511 - min(sh[i], 511)], 1); }
  }
  pref[t] = csum; __syncthreads();
  for (int o = 1; o < 256; o <<= 1){
    int v = (t >= o) ? pref[t - o] : 0;
    __syncthreads();
    pref[t] += v;
    __syncthreads();
  }
  int b0 = hist[2*t], b1 = hist[2*t + 1];
  int loc = b0 + b1;
  htmp[t] = loc; __syncthreads();
  for (int o = 1; o < 256; o <<= 1){
    int v = (t >= o) ? htmp[t - o] : 0;
    __syncthreads();
    htmp[t] += v;
    __syncthreads();
  }
  int ex = htmp[t] - loc;
  __syncthreads();
  hist[2*t] = ex; hist[2*t + 1] = ex + b0;   // scatter cursors per bin
  __syncthreads();
  int run = pref[t] - csum;
  for (int k = 0; k < PER; k++){
    int i = base + k;
    if (i < NN){
      int c = sh[i];
      A.rowptr[i] = run; run += c;
      A.dinv[i] = rsqrtf((float)c + 1.f);
      A.cursor[i] = 0;
      A.apre[i] = 0.f;
      int pos = atomicAdd(&hist[511 - min(c, 511)], 1);
      A.perm[pos] = i;
    }
  }
  if (t == 255) A.rowptr[NN] = pref[255];
}

// ===== GEMM body (bf16x3, K-step 64), callable in tile loop =====
__device__ void dev_gemm(
    const unsigned short* __restrict__ Ah, const unsigned short* __restrict__ Al,
    const unsigned short* __restrict__ Bh, const unsigned short* __restrict__ Bl,
    float* __restrict__ C, int N, int Kp, int M, int mode,
    const float* __restrict__ bias, unsigned short* __restrict__ outH,
    unsigned short* __restrict__ outL,
    const float* __restrict__ a_s, const float* __restrict__ a_d,
    float* __restrict__ as_o, float* __restrict__ ad_o, int Cdim,
    char* smem, int bid){
  unsigned short* AsH = (unsigned short*)(smem + SM_ASH);
  unsigned short* AsL = (unsigned short*)(smem + SM_ASL);
  unsigned short* BsH = (unsigned short*)(smem + SM_BSH);
  unsigned short* BsL = (unsigned short*)(smem + SM_BSL);
  float* sredf = (float*)(smem + SM_SRED);   // [2][GBM][4]
  __syncthreads();   // protect LDS reuse across consecutive tiles / phases
  int gx = M / GBN;
  int gy = (N + GBM - 1) / GBM;
  const int G = 8;
  int full = gy / G;
  int bid_full = full * G * gx;
  int by, bx;
  if (bid < bid_full){
    int g = bid / (G*gx); int rem = bid % (G*gx);
    by = g*G + rem % G; bx = rem / G;
  } else {
    int rem = bid - bid_full; int rows = gy - full*G;
    by = full*G + rem % rows; bx = rem / rows;
  }
  int row0 = by * GBM, col0 = bx * GBN;
  int t = threadIdx.x;
  int w = t >> 6, L = t & 63;
  int lm = L & 15, lq = L >> 4;
  int wc = w * 32;

  int sr = L >> 2, sc = L & 3;
  int art = w*16 + sr;
  int ga  = (sc - ((art >> 1) & 3)) & 3;
  int agrow = min(row0 + art, N-1);
  int brt0 = w*16 + sr;
  int brt1 = (w+4)*16 + sr;
  int gb0 = (sc - ((brt0 >> 1) & 3)) & 3;
  int gb1 = (sc - ((brt1 >> 1) & 3)) & 3;
  int bgrow0 = col0 + brt0, bgrow1 = col0 + brt1;

  int rc = (lq + (lm >> 1)) & 3;
  int aoff[4], boff[2];
#pragma unroll
  for (int mi = 0; mi < 4; mi++) aoff[mi] = (mi*16 + lm)*32 + rc*8;
#pragma unroll
  for (int ni = 0; ni < 2; ni++) boff[ni] = (wc + ni*16 + lm)*32 + rc*8;

  f32x4 acc[4][2];
#pragma unroll
  for (int i = 0; i < 4; i++)
#pragma unroll
    for (int j = 0; j < 2; j++) acc[i][j] = (f32x4){0.f,0.f,0.f,0.f};

  int nk = Kp / GBK;
  for (int kt = 0; kt < nk; kt++){
    int k0 = kt * GBK;
    if (kt) __syncthreads();
#pragma unroll
    for (int h = 0; h < 2; h++){
      int kh = k0 + h*32;
      gl_lds16(&Ah[(size_t)agrow*Kp + kh + ga*8],  &AsH[h*2048 + w*512]);
      gl_lds16(&Al[(size_t)agrow*Kp + kh + ga*8],  &AsL[h*2048 + w*512]);
      gl_lds16(&Bh[(size_t)bgrow0*Kp + kh + gb0*8], &BsH[h*4096 + w*512]);
      gl_lds16(&Bh[(size_t)bgrow1*Kp + kh + gb1*8], &BsH[h*4096 + (w+4)*512]);
      gl_lds16(&Bl[(size_t)bgrow0*Kp + kh + gb0*8], &BsL[h*4096 + w*512]);
      gl_lds16(&Bl[(size_t)bgrow1*Kp + kh + gb1*8], &BsL[h*4096 + (w+4)*512]);
    }
    __syncthreads();
#pragma unroll
    for (int h = 0; h < 2; h++){
      short8 ah[4], al[4], bh[2], bl[2];
#pragma unroll
      for (int mi = 0; mi < 4; mi++){
        ah[mi] = *(const short8*)&AsH[h*2048 + aoff[mi]];
        al[mi] = *(const short8*)&AsL[h*2048 + aoff[mi]];
      }
#pragma unroll
      for (int ni = 0; ni < 2; ni++){
        bh[ni] = *(const short8*)&BsH[h*4096 + boff[ni]];
        bl[ni] = *(const short8*)&BsL[h*4096 + boff[ni]];
      }
#pragma unroll
      for (int mi = 0; mi < 4; mi++)
#pragma unroll
        for (int ni = 0; ni < 2; ni++){
          acc[mi][ni] = __builtin_amdgcn_mfma_f32_16x16x32_bf16(ah[mi], bh[ni], acc[mi][ni], 0, 0, 0);
          acc[mi][ni] = __builtin_amdgcn_mfma_f32_16x16x32_bf16(ah[mi], bl[ni], acc[mi][ni], 0, 0, 0);
          acc[mi][ni] = __builtin_amdgcn_mfma_f32_16x16x32_bf16(al[mi], bh[ni], acc[mi][ni], 0, 0, 0);
        }
    }
  }
  if (mode == 1){
#pragma unroll
    for (int mi = 0; mi < 4; mi++)
#pragma unroll
      for (int ni = 0; ni < 2; ni++){
#pragma unroll
        for (int r = 0; r < 4; r++){
          int row = row0 + mi*16 + lq*4 + r;
          int col = col0 + wc + ni*16 + lm;
          if (row < N){
            float v = fmaxf(acc[mi][ni][r] + bias[col], 0.f);
            unsigned short hh, ll; split2(v, hh, ll);
            outH[(size_t)row*M + col] = hh;
            outL[(size_t)row*M + col] = ll;
            C[(size_t)row*M + col] = v;
          }
        }
      }
  } else if (mode != 3){
#pragma unroll
    for (int mi = 0; mi < 4; mi++)
#pragma unroll
      for (int ni = 0; ni < 2; ni++){
#pragma unroll
        for (int r = 0; r < 4; r++){
          int row = row0 + mi*16 + lq*4 + r;
          int col = col0 + wc + ni*16 + lm;
          if (row < N) C[(size_t)row*M + col] = acc[mi][ni][r];
        }
      }
  }
  if (mode == 2){
    float sA0 = a_s[col0 + wc + lm], sA1 = a_s[col0 + wc + 16 + lm];
    float dA0 = a_d[col0 + wc + lm], dA1 = a_d[col0 + wc + 16 + lm];
#pragma unroll
    for (int mi = 0; mi < 4; mi++)
#pragma unroll
      for (int r = 0; r < 4; r++){
        float vs = acc[mi][0][r]*sA0 + acc[mi][1][r]*sA1;
        float vd = acc[mi][0][r]*dA0 + acc[mi][1][r]*dA1;
#pragma unroll
        for (int o = 1; o <= 8; o <<= 1){
          vs += __shfl_xor(vs, o);
          vd += __shfl_xor(vd, o);
        }
        if (lm == 0){
          int row = mi*16 + lq*4 + r;
          sredf[(0*GBM + row)*4 + w] = vs;
          sredf[(1*GBM + row)*4 + w] = vd;
        }
      }
    __syncthreads();
    if (t < GBM){
      int n = row0 + t;
      if (n < N){
        int wph = Cdim >> 5;
        int nheads = 4 / wph;
        for (int g = 0; g < nheads; g++){
          float ss = 0.f, dd = 0.f;
          for (int q = 0; q < wph; q++){
            ss += sredf[(0*GBM + t)*4 + g*wph + q];
            dd += sredf[(1*GBM + t)*4 + g*wph + q];
          }
          int hd = (col0 + g*wph*32) / Cdim;
          as_o[n*NH + hd] = ss;
          ad_o[n*NH + hd] = dd;
        }
      }
    }
  } else if (mode == 3){
    float b0 = bias[col0 + wc + lm], b1v = bias[col0 + wc + 16 + lm];
    float w0v = a_s[col0 + wc + lm], w1v = a_s[col0 + wc + 16 + lm];
#pragma unroll
    for (int mi = 0; mi < 4; mi++)
#pragma unroll
      for (int r = 0; r < 4; r++){
        float v = tanhf(acc[mi][0][r] + b0)*w0v + tanhf(acc[mi][1][r] + b1v)*w1v;
#pragma unroll
        for (int o = 1; o <= 8; o <<= 1) v += __shfl_xor(v, o);
        if (lm == 0) sredf[(mi*16 + lq*4 + r)*4 + w] = v;
      }
    __syncthreads();
    if (t < GBM){
      int n = row0 + t;
      if (n < N){
        float s = sredf[t*4+0] + sredf[t*4+1] + sredf[t*4+2] + sredf[t*4+3];
        atomicAdd(&as_o[n], s);
      }
    }
  }
}

// ===== GCN pre-agg layer 0 =====
__device__ void dev_pre0(const MegaArgs& A, int tile){
  int t = threadIdx.x;
  int sub = t & 15;
  int gid = tile*16 + (t >> 4);
  int n = A.perm[gid];
  int f0 = sub*4;
  bool act = f0 < 36;
  int b = A.rowptr[n], e = A.rowptr[n+1];
  float dn = A.dinv[n];
  const float* x0 = A.x0;
  const int* colidx = A.colidx;
  const float* dinv = A.dinv;
  float4 a0 = make_float4(0,0,0,0), a1 = make_float4(0,0,0,0);
  float4 a2 = make_float4(0,0,0,0), a3 = make_float4(0,0,0,0);
  if (act){
    float4 sv = *(const float4*)&x0[(size_t)n*36 + f0];
    int j = b;
    for (; j + 7 < e; j += 8){
      int s0 = colidx[j],   s1 = colidx[j+1], s2 = colidx[j+2], s3 = colidx[j+3];
      int s4 = colidx[j+4], s5 = colidx[j+5], s6 = colidx[j+6], s7 = colidx[j+7];
      float w0 = dinv[s0], w1 = dinv[s1], w2 = dinv[s2], w3 = dinv[s3];
      float w4 = dinv[s4], w5 = dinv[s5], w6 = dinv[s6], w7 = dinv[s7];
      float4 v0 = *(const float4*)&x0[(size_t)s0*36 + f0];
      float4 v1 = *(const float4*)&x0[(size_t)s1*36 + f0];
      float4 v2 = *(const float4*)&x0[(size_t)s2*36 + f0];
      float4 v3 = *(const float4*)&x0[(size_t)s3*36 + f0];
      float4 v4 = *(const float4*)&x0[(size_t)s4*36 + f0];
      float4 v5 = *(const float4*)&x0[(size_t)s5*36 + f0];
      float4 v6 = *(const float4*)&x0[(size_t)s6*36 + f0];
      float4 v7 = *(const float4*)&x0[(size_t)s7*36 + f0];
      fma4(a0, v0, w0*dn); fma4(a1, v1, w1*dn);
      fma4(a2, v2, w2*dn); fma4(a3, v3, w3*dn);
      fma4(a0, v4, w4*dn); fma4(a1, v5, w5*dn);
      fma4(a2, v6, w6*dn); fma4(a3, v7, w7*dn);
    }
    for (; j + 3 < e; j += 4){
      int s0 = colidx[j], s1 = colidx[j+1], s2 = colidx[j+2], s3 = colidx[j+3];
      float w0 = dinv[s0], w1 = dinv[s1], w2 = dinv[s2], w3 = dinv[s3];
      float4 v0 = *(const float4*)&x0[(size_t)s0*36 + f0];
      float4 v1 = *(const float4*)&x0[(size_t)s1*36 + f0];
      float4 v2 = *(const float4*)&x0[(size_t)s2*36 + f0];
      float4 v3 = *(const float4*)&x0[(size_t)s3*36 + f0];
      fma4(a0, v0, w0*dn); fma4(a1, v1, w1*dn);
      fma4(a2, v2, w2*dn); fma4(a3, v3, w3*dn);
    }
    for (; j < e; j++){
      int s = colidx[j];
      float4 v = *(const float4*)&x0[(size_t)s*36 + f0];
      fma4(a0, v, dinv[s]*dn);
    }
    float4 acc = make_float4(a0.x+a1.x+a2.x+a3.x, a0.y+a1.y+a2.y+a3.y,
                             a0.z+a1.z+a2.z+a3.z, a0.w+a1.w+a2.w+a3.w);
    float dn2 = dn*dn;
    acc.x += sv.x*dn2; acc.y += sv.y*dn2; acc.z += sv.z*dn2; acc.w += sv.w*dn2;
    store_hl(A.preH, A.preL, (size_t)n*64 + f0, acc);
  } else {
    store_hl(A.preH, A.preL, (size_t)n*64 + f0, make_float4(0,0,0,0));
  }
}

// ===== GCN pre-agg layers 1..2 =====
__device__ void dev_pre(const MegaArgs& A, int tile, int Kp, int nchunk){
  int chunk = tile % nchunk, grp = tile / nchunk;
  int t = threadIdx.x;
  int sub = t & 15;
  int gid = grp*16 + (t >> 4);
  int n = A.perm[gid];
  int f0 = chunk*64 + sub*4;
  int b = A.rowptr[n], e = A.rowptr[n+1];
  float dn = A.dinv[n];
  const float* xf = A.xf;
  const int* colidx = A.colidx;
  const float* dinv = A.dinv;
  float4 sv = *(const float4*)&xf[(size_t)n*Kp + f0];
  float4 a0 = make_float4(0,0,0,0), a1 = make_float4(0,0,0,0);
  float4 a2 = make_float4(0,0,0,0), a3 = make_float4(0,0,0,0);
  int j = b;
  for (; j + 7 < e; j += 8){
    int s0 = colidx[j],   s1 = colidx[j+1], s2 = colidx[j+2], s3 = colidx[j+3];
    int s4 = colidx[j+4], s5 = colidx[j+5], s6 = colidx[j+6], s7 = colidx[j+7];
    float w0 = dinv[s0], w1 = dinv[s1], w2 = dinv[s2], w3 = dinv[s3];
    float w4 = dinv[s4], w5 = dinv[s5], w6 = dinv[s6], w7 = dinv[s7];
    float4 v0 = *(const float4*)&xf[(size_t)s0*Kp + f0];
    float4 v1 = *(const float4*)&xf[(size_t)s1*Kp + f0];
    float4 v2 = *(const float4*)&xf[(size_t)s2*Kp + f0];
    float4 v3 = *(const float4*)&xf[(size_t)s3*Kp + f0];
    float4 v4 = *(const float4*)&xf[(size_t)s4*Kp + f0];
    float4 v5 = *(const float4*)&xf[(size_t)s5*Kp + f0];
    float4 v6 = *(const float4*)&xf[(size_t)s6*Kp + f0];
    float4 v7 = *(const float4*)&xf[(size_t)s7*Kp + f0];
    fma4(a0, v0, w0*dn); fma4(a1, v1, w1*dn);
    fma4(a2, v2, w2*dn); fma4(a3, v3, w3*dn);
    fma4(a0, v4, w4*dn); fma4(a1, v5, w5*dn);
    fma4(a2, v6, w6*dn); fma4(a3, v7, w7*dn);
  }
  for (; j + 3 < e; j += 4){
    int s0 = colidx[j], s1 = colidx[j+1], s2 = colidx[j+2], s3 = colidx[j+3];
    float w0 = dinv[s0], w1 = dinv[s1], w2 = dinv[s2], w3 = dinv[s3];
    float4 v0 = *(const float4*)&xf[(size_t)s0*Kp + f0];
    float4 v1 = *(const float4*)&xf[(size_t)s1*Kp + f0];
    float4 v2 = *(const float4*)&xf[(size_t)s2*Kp + f0];
    float4 v3 = *(const float4*)&xf[(size_t)s3*Kp + f0];
    fma4(a0, v0, w0*dn); fma4(a1, v1, w1*dn);
    fma4(a2, v2, w2*dn); fma4(a3, v3, w3*dn);
  }
  for (; j < e; j++){
    int s = colidx[j];
    float4 v = *(const float4*)&xf[(size_t)s*Kp + f0];
    fma4(a0, v, dinv[s]*dn);
  }
  float4 acc = make_float4(a0.x+a1.x+a2.x+a3.x, a0.y+a1.y+a2.y+a3.y,
                           a0.z+a1.z+a2.z+a3.z, a0.w+a1.w+a2.w+a3.w);
  float dn2 = dn*dn;
  acc.x += sv.x*dn2; acc.y += sv.y*dn2; acc.z += sv.z*dn2; acc.w += sv.w*dn2;
  store_hl(A.preH, A.preL, (size_t)n*Kp + f0, acc);
}

// ===== GAT gather (fixed-shift softmax) =====
__device__ void dev_gat(const MegaArgs& A, int tile, int M, int C, int nchunk, bool writeHL){
  int chunk = tile % nchunk, grp = tile / nchunk;
  int t = threadIdx.x;
  int sub = t & 15;
  int gid = grp*16 + (t >> 4);
  int n = A.perm[gid];
  int f0 = chunk*64 + sub*4;
  int hd = f0 / C;
  int b = A.rowptr[n], e = A.rowptr[n+1];
  const float* hg = A.f1;
  const int* colidx = A.colidx;
  const float* as_ = A.as_;
  int ai = n*NH + hd;
  float adn = A.ad_[ai];
  float sl = fminf(fmaxf(leakyf(as_[ai] + adn), -80.f), 80.f);
  float es = __expf(sl);
  float4 sv = *(const float4*)&hg[(size_t)n*M + f0];
  float4 hv = *(const float4*)&A.hf[(size_t)n*M + f0];
  float4 bb = *(const float4*)&A.ab[0][0];   // placeholder overwritten below
  bb = *(const float4*)&A.ab[(M==128)?0:((M==256)?1:2)][f0];
  float d = es;
  float4 a0 = make_float4(0,0,0,0), a1 = make_float4(0,0,0,0);
  float4 a2 = make_float4(0,0,0,0), a3 = make_float4(0,0,0,0);
  int j = b;
  for (; j + 7 < e; j += 8){
    int s0 = colidx[j],   s1 = colidx[j+1], s2 = colidx[j+2], s3 = colidx[j+3];
    int s4 = colidx[j+4], s5 = colidx[j+5], s6 = colidx[j+6], s7 = colidx[j+7];
    float l0 = leakyf(as_[s0*NH + hd] + adn), l1 = leakyf(as_[s1*NH + hd] + adn);
    float l2 = leakyf(as_[s2*NH + hd] + adn), l3 = leakyf(as_[s3*NH + hd] + adn);
    float l4 = leakyf(as_[s4*NH + hd] + adn), l5 = leakyf(as_[s5*NH + hd] + adn);
    float l6 = leakyf(as_[s6*NH + hd] + adn), l7 = leakyf(as_[s7*NH + hd] + adn);
    float4 v0 = *(const float4*)&hg[(size_t)s0*M + f0];
    float4 v1 = *(const float4*)&hg[(size_t)s1*M + f0];
    float4 v2 = *(const float4*)&hg[(size_t)s2*M + f0];
    float4 v3 = *(const float4*)&hg[(size_t)s3*M + f0];
    float4 v4 = *(const float4*)&hg[(size_t)s4*M + f0];
    float4 v5 = *(const float4*)&hg[(size_t)s5*M + f0];
    float4 v6 = *(const float4*)&hg[(size_t)s6*M + f0];
    float4 v7 = *(const float4*)&hg[(size_t)s7*M + f0];
    float w0 = __expf(fminf(fmaxf(l0,-80.f),80.f)), w1 = __expf(fminf(fmaxf(l1,-80.f),80.f));
    float w2 = __expf(fminf(fmaxf(l2,-80.f),80.f)), w3 = __expf(fminf(fmaxf(l3,-80.f),80.f));
    float w4 = __expf(fminf(fmaxf(l4,-80.f),80.f)), w5 = __expf(fminf(fmaxf(l5,-80.f),80.f));
    float w6 = __expf(fminf(fmaxf(l6,-80.f),80.f)), w7 = __expf(fminf(fmaxf(l7,-80.f),80.f));
    d += ((w0 + w1) + (w2 + w3)) + ((w4 + w5) + (w6 + w7));
    fma4(a0, v0, w0); fma4(a1, v1, w1);
    fma4(a2, v2, w2); fma4(a3, v3, w3);
    fma4(a0, v4, w4); fma4(a1, v5, w5);
    fma4(a2, v6, w6); fma4(a3, v7, w7);
  }
  for (; j < e; j++){
    int s = colidx[j];
    float l = leakyf(as_[s*NH + hd] + adn);
    float4 v = *(const float4*)&hg[(size_t)s*M + f0];
    float ww = __expf(fminf(fmaxf(l,-80.f),80.f));
    d += ww;
    fma4(a0, v, ww);
  }
  float4 acc = make_float4(a0.x+a1.x+a2.x+a3.x, a0.y+a1.y+a2.y+a3.y,
                           a0.z+a1.z+a2.z+a3.z, a0.w+a1.w+a2.w+a3.w);
  float inv = 1.f/d;
  float4 r = make_float4(
    hv.x + bb.x + (sv.x*es + acc.x)*inv,
    hv.y + bb.y + (sv.y*es + acc.y)*inv,
    hv.z + bb.z + (sv.z*es + acc.z)*inv,
    hv.w + bb.w + (sv.w*es + acc.w)*inv);
  *(float4*)&A.xf[(size_t)n*M + f0] = r;
  if (writeHL) store_hl(A.actH1, A.actL1, (size_t)n*M + f0, r);
}

// ===== pooling (256 threads, 2 tiles/graph) =====
__device__ void dev_pool(const MegaArgs& A, int tile, char* smem){
  float* red = (float*)(smem + PL_RED);
  float4* comb = (float4*)(smem + PL_COMB);   // [3][4][64]
  int g = tile >> 1, half = tile & 1, t = threadIdx.x;
  __syncthreads();
  int b = A.starts[g], e = A.starts[g+1];
  const float* apre = A.apre;
  float m = -INFINITY;
  for (int n = b + t; n < e; n += 256) m = fmaxf(m, apre[n]);
  red[t] = m; __syncthreads();
  for (int o = 128; o > 0; o >>= 1){
    if (t < o) red[t] = fmaxf(red[t], red[t + o]);
    __syncthreads();
  }
  m = red[0]; __syncthreads();
  float s = 0.f;
  for (int n = b + t; n < e; n += 256) s += __expf(apre[n] - m);
  red[t] = s; __syncthreads();
  for (int o = 128; o > 0; o >>= 1){
    if (t < o) red[t] += red[t + o];
    __syncthreads();
  }
  float inv = 1.f / (red[0] + 1e-8f);
  int lf = t & 63, slc = t >> 6;       // 64 float4 feats × 4 node slices
  int fo = half*64 + lf;
  float4 sum = make_float4(0,0,0,0), wacc = make_float4(0,0,0,0);
  float4 mx = make_float4(-INFINITY,-INFINITY,-INFINITY,-INFINITY);
  for (int n = b + slc; n < e; n += 4){
    float4 xv = *(const float4*)&A.xf[(size_t)n*DOUT + fo*4];
    float p = __expf(apre[n] - m) * inv;
    sum.x += xv.x; sum.y += xv.y; sum.z += xv.z; sum.w += xv.w;
    mx.x = fmaxf(mx.x, xv.x); mx.y = fmaxf(mx.y, xv.y);
    mx.z = fmaxf(mx.z, xv.z); mx.w = fmaxf(mx.w, xv.w);
    fma4(wacc, xv, p);
  }
  comb[(0*4 + slc)*64 + lf] = wacc;
  comb[(1*4 + slc)*64 + lf] = sum;
  comb[(2*4 + slc)*64 + lf] = mx;
  __syncthreads();
  if (slc == 0){
#pragma unroll
    for (int q = 1; q < 4; q++){
      float4 w2 = comb[(0*4+q)*64+lf], s2 = comb[(1*4+q)*64+lf], m2 = comb[(2*4+q)*64+lf];
      wacc.x += w2.x; wacc.y += w2.y; wacc.z += w2.z; wacc.w += w2.w;
      sum.x += s2.x; sum.y += s2.y; sum.z += s2.z; sum.w += s2.w;
      mx.x = fmaxf(mx.x, m2.x); mx.y = fmaxf(mx.y, m2.y);
      mx.z = fmaxf(mx.z, m2.z); mx.w = fmaxf(mx.w, m2.w);
    }
    float ic = 1.f / fmaxf((float)(e - b), 1.f);
    float4* o = (float4*)(A.out + (size_t)g*4*DOUT);
    o[fo]       = wacc;
    o[128 + fo] = make_float4(sum.x*ic, sum.y*ic, sum.z*ic, sum.w*ic);
    o[256 + fo] = mx;
    o[384 + fo] = sum;
  }
}

// ============================ mega kernel (cooperative) ============================
__global__ __launch_bounds__(256) void k_mega(MegaArgs A){
  cg::grid_group gg = cg::this_grid();
  __shared__ char smem[SMEM_SZ];
  int nb = gridDim.x, bid = blockIdx.x, t = threadIdx.x;
  int stride = nb*256, tid = bid*256 + t;

  for (int i = tid; i < NE; i += stride) atomicAdd(&A.cnt[A.dst[i]], 1);
  for (int i = tid; i < A.convTot; i += stride) dev_conv(A, i);
  gg.sync();
  if (bid == 0) dev_scan256(A, smem);
  gg.sync();
  for (int e = tid; e < NE; e += stride) dev_fill(A, e);
  gg.sync();

  const int dims[4] = {36, 128, 256, 512};
  for (int layer = 0; layer < 3; layer++){
    int wi = layer*2;
    int Kin = (layer == 0) ? 64 : dims[layer];
    int M = dims[layer+1], C = M/NH;
    int nin = Kin/64, nch = M/64;
    int gy = (NN + GBM - 1)/GBM;
    int nblk = (M/GBN)*gy;
    if (layer == 0){
      for (int tl = bid; tl < 625; tl += nb) dev_pre0(A, tl);
    } else {
      for (int tl = bid; tl < nin*625; tl += nb) dev_pre(A, tl, Kin, nin);
    }
    gg.sync();
    for (int tl = bid; tl < nblk; tl += nb)
      dev_gemm(A.preH, A.preL, A.wTh[wi], A.wTl[wi], A.hf, NN, A.wKp[wi], M, 1,
               A.gb[layer], A.actH0, A.actL0, nullptr, nullptr, nullptr, nullptr, C, smem, tl);
    gg.sync();
    for (int tl = bid; tl < nblk; tl += nb)
      dev_gemm(A.actH0, A.actL0, A.wTh[wi+1], A.wTl[wi+1], A.f1, NN, A.wKp[wi+1], M, 2,
               nullptr, nullptr, nullptr, A.asw[layer], A.adw[layer], A.as_, A.ad_, C, smem, tl);
    gg.sync();
    for (int tl = bid; tl < nch*625; tl += nb) dev_gat(A, tl, M, C, nch, layer == 2);
    gg.sync();
  }
  {
    int nblk = (256/GBN)*((NN + GBM - 1)/GBM);
    for (int tl = bid; tl < nblk; tl += nb)
      dev_gemm(A.actH1, A.actL1, A.wTh[6], A.wTl[6], nullptr, NN, A.wKp[6], 256, 3,
               A.apb1, nullptr, nullptr, A.apw2v, nullptr, A.apre, nullptr, 64, smem, tl);
    gg.sync();
    for (int tl = bid; tl < NB*2; tl += nb) dev_pool(A, tl, smem);
  }
}

// ============================ fallback wrappers ============================
__global__ void k_count_conv_fb(MegaArgs A){
  int bid = blockIdx.x;
  if (bid < CNT_BLKS){
    int e = bid*256 + threadIdx.x;
    if (e < NE) atomicAdd(&A.cnt[A.dst[e]], 1);
  } else {
    int idx = (bid - CNT_BLKS)*256 + threadIdx.x;
    if (idx < A.convTot) dev_conv(A, idx);
  }
}
__global__ __launch_bounds__(256) void k_scan_fb(MegaArgs A){
  __shared__ char s[SCAN_SZ];
  dev_scan256(A, s);
}
__global__ void k_fill_fb(MegaArgs A){
  int e = blockIdx.x*256 + threadIdx.x;
  if (e < NE) dev_fill(A, e);
}
__global__ __launch_bounds__(256) void k_pre0_fb(MegaArgs A){ dev_pre0(A, blockIdx.x); }
__global__ __launch_bounds__(256) void k_pre_fb(MegaArgs A, int Kp, int nch){
  dev_pre(A, blockIdx.x, Kp, nch);
}
__global__ __launch_bounds__(256) void k_gemm_fb(
    const unsigned short* Ah, const unsigned short* Al,
    const unsigned short* Bh, const unsigned short* Bl,
    float* C, int N, int Kp, int M, int mode, const float* bias,
    unsigned short* outH, unsigned short* outL,
    const float* a_s, const float* a_d, float* as_o, float* ad_o, int Cdim){
  __shared__ char s[SMEM_SZ];
  dev_gemm(Ah, Al, Bh, Bl, C, N, Kp, M, mode, bias, outH, outL, a_s, a_d, as_o, ad_o, Cdim, s, blockIdx.x);
}
__global__ __launch_bounds__(256) void k_gat_fb(MegaArgs A, int M, int C, int nch, int wHL){
  dev_gat(A, blockIdx.x, M, C, nch, wHL != 0);
}
__global__ __launch_bounds__(256) void k_pool_fb(MegaArgs A){
  __shared__ char s[POOL_SZ];
  dev_pool(A, blockIdx.x, s);
}

// ============================ host ============================
extern "C" void kernel_launch(void* const* d_in, const int* in_sizes, int n_in,
                              void* d_out, int out_size, void* d_ws, size_t ws_size,
                              hipStream_t stream) {
  const float* x0   = (const float*)d_in[0];
  const int*   ei   = (const int*)d_in[1];
  const int*   src  = ei;
  const int*   dst  = ei + NE;
  const int*   batch= (const int*)d_in[2];
  const float* gw[3]  = {(const float*)d_in[3],  (const float*)d_in[9],  (const float*)d_in[15]};
  const float* gb[3]  = {(const float*)d_in[4],  (const float*)d_in[10], (const float*)d_in[16]};
  const float* aw[3]  = {(const float*)d_in[5],  (const float*)d_in[11], (const float*)d_in[17]};
  const float* asw[3] = {(const float*)d_in[6],  (const float*)d_in[12], (const float*)d_in[18]};
  const float* adw[3] = {(const float*)d_in[7],  (const float*)d_in[13], (const float*)d_in[19]};
  const float* ab[3]  = {(const float*)d_in[8],  (const float*)d_in[14], (const float*)d_in[20]};
  const float* apw1 = (const float*)d_in[21];
  const float* apb1 = (const float*)d_in[22];
  const float* apw2 = (const float*)d_in[23];
  float* out = (float*)d_out;

  char* p = (char*)d_ws;
  auto alloc = [&](size_t bytes) -> void* {
    void* r = (void*)p; p += (bytes + 255) & ~(size_t)255; return r;
  };
  MegaArgs A;
  A.x0 = x0; A.src = src; A.dst = dst; A.batch = batch; A.out = out;
  A.f1 = (float*)alloc((size_t)NN*512*4);
  A.hf = (float*)alloc((size_t)NN*512*4);
  A.xf = (float*)alloc((size_t)NN*512*4);
  A.actH0 = (unsigned short*)alloc((size_t)NN*512*2);
  A.actL0 = (unsigned short*)alloc((size_t)NN*512*2);
  A.actH1 = (unsigned short*)alloc((size_t)NN*512*2);
  A.actL1 = (unsigned short*)alloc((size_t)NN*512*2);
  A.preH  = (unsigned short*)alloc((size_t)NN*256*2);
  A.preL  = (unsigned short*)alloc((size_t)NN*256*2);
  const int wK[7]  = {36, 128, 128, 256, 256, 512, 512};
  const int wM[7]  = {128, 128, 256, 256, 512, 512, 256};
  const int wKp[7] = {64, 128, 128, 256, 256, 512, 512};
  const float* wsrc[7] = {gw[0], aw[0], gw[1], aw[1], gw[2], aw[2], apw1};
  int convTot = 0;
  for (int i = 0; i < 7; i++){
    size_t sz = (size_t)wM[i]*wKp[i]*2;
    unsigned short* th = (unsigned short*)alloc(sz);
    unsigned short* tl = (unsigned short*)alloc(sz);
    A.wTh[i] = th; A.wTl[i] = tl; A.wdh[i] = th; A.wdl[i] = tl;
    A.wsrc[i] = wsrc[i];
    A.wK[i] = wK[i]; A.wM[i] = wM[i]; A.wKp[i] = wKp[i];
    A.wTot[i] = wKp[i]*wM[i];
    convTot += A.wTot[i];
  }
  A.convTot = convTot;
  A.dinv = (float*)alloc(NN*4);
  A.as_  = (float*)alloc(NN*NH*4);
  A.ad_  = (float*)alloc(NN*NH*4);
  A.apre = (float*)alloc(NN*4);
  A.rowptr = (int*)alloc((NN+1)*4);
  A.colidx = (int*)alloc((size_t)NE*4);
  A.cnt    = (int*)alloc(NN*4);
  A.cursor = (int*)alloc(NN*4);
  A.starts = (int*)alloc((NB+1)*4);
  A.perm   = (int*)alloc(NN*4);
  for (int i = 0; i < 3; i++){
    A.gb[i] = gb[i]; A.asw[i] = asw[i]; A.adw[i] = adw[i]; A.ab[i] = ab[i];
  }
  A.apb1 = apb1; A.apw2v = apw2;

  hipMemsetAsync(A.cnt, 0, NN*sizeof(int), stream);

  // ---- try cooperative mega-kernel ----
  int perCU = 0;
  hipError_t qe = hipOccupancyMaxActiveBlocksPerMultiprocessor(&perCU, k_mega, 256, 0);
  if (qe != hipSuccess || perCU < 1) perCU = 1;
  int grid = perCU * 256;
  if (grid > 768) grid = 768;
  void* kargs[] = { (void*)&A };
  hipError_t ce = hipLaunchCooperativeKernel((void*)k_mega, dim3(grid), dim3(256),
                                             kargs, 0, stream);
  if (ce == hipSuccess) return;

  // ---- fallback: individual launches (same device code) ----
  int convBlks = (convTot + 255) / 256;
  k_count_conv_fb<<<CNT_BLKS + convBlks, 256, 0, stream>>>(A);
  k_scan_fb<<<1, 256, 0, stream>>>(A);
  k_fill_fb<<<(NE+255)/256, 256, 0, stream>>>(A);
  const int dims[4] = {36, 128, 256, 512};
  for (int i = 0; i < 3; i++){
    int wi = i*2;
    int Kin = (i == 0) ? 64 : dims[i];
    int M = dims[i+1], C = M/NH;
    int nin = Kin/64, nch = M/64;
    int nblk = (M/GBN) * ((NN+GBM-1)/GBM);
    if (i == 0){
      k_pre0_fb<<<625, 256, 0, stream>>>(A);
    } else {
      k_pre_fb<<<nin*625, 256, 0, stream>>>(A, Kin, nin);
    }
    k_gemm_fb<<<nblk, 256, 0, stream>>>(A.preH, A.preL, A.wTh[wi], A.wTl[wi], A.hf,
                                        NN, A.wKp[wi], M, 1, A.gb[i], A.actH0, A.actL0,
                                        nullptr, nullptr, nullptr, nullptr, C);
    k_gemm_fb<<<nblk, 256, 0, stream>>>(A.actH0, A.actL0, A.wTh[wi+1], A.wTl[wi+1], A.f1,
                                        NN, A.wKp[wi+1], M, 2, nullptr, nullptr, nullptr,
                                        A.asw[i], A.adw[i], A.as_, A.ad_, C);
    k_gat_fb<<<nch*625, 256, 0, stream>>>(A, M, C, nch, (i == 2) ? 1 : 0);
  }
  {
    int nblk = (256/GBN) * ((NN+GBM-1)/GBM);
    k_gemm_fb<<<nblk, 256, 0, stream>>>(A.actH1, A.actL1, A.wTh[6], A.wTl[6], nullptr,
                                        NN, A.wKp[6], 256, 3, A.apb1, nullptr, nullptr,
                                        A.apw2v, nullptr, A.apre, nullptr, 64);
  }
  k_pool_fb<<<NB*2, 256, 0, stream>>>(A);
}

// Round 7
// 376.583 us; speedup vs baseline: 2.8309x; 2.8309x over previous
//
#include <hip/hip_runtime.h>
#include <math.h>

#define NN 10000
#define NE 160000
#define NB 128
#define NH 4
#define DOUT 512
#define NEG 0.2f
#define CNT_BLKS ((NE + 255) / 256)    // 625

typedef __attribute__((ext_vector_type(8))) short short8;
typedef __attribute__((ext_vector_type(4))) float f32x4;
typedef __attribute__((ext_vector_type(4))) unsigned short us4;

__device__ __forceinline__ float leakyf(float v){ return fmaxf(v, NEG*v); }
__device__ __forceinline__ void fma4(float4& a, const float4 v, float w){
  a.x += v.x*w; a.y += v.y*w; a.z += v.z*w; a.w += v.w*w;
}
__device__ __forceinline__ unsigned short f2bf(float f){
  unsigned int u = __float_as_uint(f);
  u += 0x7FFFu + ((u >> 16) & 1u);
  return (unsigned short)(u >> 16);
}
__device__ __forceinline__ float bf2f(unsigned short h){
  return __uint_as_float(((unsigned int)h) << 16);
}
__device__ __forceinline__ void split2(float v, unsigned short& h, unsigned short& l){
  h = f2bf(v);
  l = f2bf(v - bf2f(h));
}
__device__ __forceinline__ void store_hl(unsigned short* H, unsigned short* L,
                                         size_t base, float4 v){
  us4 h, l; unsigned short hh, ll;
  split2(v.x, hh, ll); h[0]=hh; l[0]=ll;
  split2(v.y, hh, ll); h[1]=hh; l[1]=ll;
  split2(v.z, hh, ll); h[2]=hh; l[2]=ll;
  split2(v.w, hh, ll); h[3]=hh; l[3]=ll;
  *(us4*)&H[base] = h;
  *(us4*)&L[base] = l;
}
__device__ __forceinline__ void gl_lds16(const unsigned short* g, unsigned short* l){
  __builtin_amdgcn_global_load_lds(
      (const __attribute__((address_space(1))) unsigned int*)g,
      (__attribute__((address_space(3))) unsigned int*)l, 16, 0, 0);
}

// ============ conversions descriptor (weights only; x0 handled by k_gcn_pre0) ============
struct AllConv {
  const float* src[7];
  unsigned short* dh[7];
  unsigned short* dl[7];
  int K[7], Mm[7], Kp[7], tot[7];
};

// ===== merged: edge count (blocks [0,CNT_BLKS)) + weight conversions (rest) =====
__global__ void k_count_conv(const int* __restrict__ dst, int* __restrict__ cnt,
                             AllConv a, int convTot){
  int bid = blockIdx.x;
  if (bid < CNT_BLKS){
    int e = bid*256 + threadIdx.x;
    if (e < NE) atomicAdd(&cnt[dst[e]], 1);
  } else {
    int idx = (bid - CNT_BLKS)*256 + threadIdx.x;
    if (idx >= convTot) return;
    int j = 0;
    while (idx >= a.tot[j]){ idx -= a.tot[j]; j++; }
    int Kp = a.Kp[j], K = a.K[j], M = a.Mm[j];
    int kk = idx % Kp, m = idx / Kp;
    float v = (kk < K) ? a.src[j][(size_t)kk*M + m] : 0.f;
    unsigned short h, l; split2(v, h, l);
    a.dh[j][idx] = h; a.dl[j][idx] = l;
  }
}

// ===== single-block scan: rowptr/dinv/cursor/apre/starts + degree-sorted perm =====
__global__ __launch_bounds__(1024) void k_scan_all(
    const int* __restrict__ cnt, const int* __restrict__ batch,
    int* __restrict__ rowptr, float* __restrict__ dinv,
    int* __restrict__ cursor, float* __restrict__ apre,
    int* __restrict__ starts, int* __restrict__ perm){
  __shared__ int sh[NN];      // 40 KB
  __shared__ int pref[1024];
  __shared__ int hist[512];
  __shared__ int hbase[512];
  int t = threadIdx.x;
  for (int i = t; i < NN; i += 1024) sh[i] = cnt[i];
  if (t < 512) hist[t] = 0;
  if (t <= NB){
    int lo = 0, hi = NN;
    while (lo < hi){ int mid = (lo + hi) >> 1; if (batch[mid] < t) lo = mid + 1; else hi = mid; }
    starts[t] = lo;
  }
  __syncthreads();
  int base = t*10;
  int csum = 0;
#pragma unroll
  for (int k = 0; k < 10; k++){
    int i = base + k;
    if (i < NN){
      csum += sh[i];
      atomicAdd(&hist[511 - min(sh[i], 511)], 1);   // descending degree bins
    }
  }
  pref[t] = csum; __syncthreads();     // histogram + csum complete
  int horig = (t < 512) ? hist[t] : 0;
  for (int o = 1; o < 1024; o <<= 1){
    int v = (t >= o) ? pref[t - o] : 0;
    __syncthreads();
    pref[t] += v;
    __syncthreads();
  }
  for (int o = 1; o < 512; o <<= 1){
    int v = 0;
    if (t < 512 && t >= o) v = hist[t - o];
    __syncthreads();
    if (t < 512 && t >= o) hist[t] += v;
    __syncthreads();
  }
  if (t < 512) hbase[t] = hist[t] - horig;   // exclusive prefix -> scatter cursor
  __syncthreads();
  int run = pref[t] - csum;   // exclusive prefix of degrees
#pragma unroll
  for (int k = 0; k < 10; k++){
    int i = base + k;
    if (i < NN){
      int c = sh[i];
      rowptr[i] = run;
      run += c;
      dinv[i] = rsqrtf((float)c + 1.f);
      cursor[i] = 0;
      apre[i] = 0.f;
      int pos = atomicAdd(&hbase[511 - min(c, 511)], 1);
      perm[pos] = i;
    }
  }
  if (t == 1023) rowptr[NN] = pref[1023];
}

__global__ void k_fill(const int* __restrict__ src, const int* __restrict__ dst,
                       const int* __restrict__ rowptr, int* __restrict__ cursor,
                       int* __restrict__ colidx){
  int e = blockIdx.x*blockDim.x + threadIdx.x;
  if (e >= NE) return;
  int d = dst[e];
  int pos = atomicAdd(&cursor[d], 1);
  colidx[rowptr[d] + pos] = src[e];
}

// ===== GEMM: C[N,M] = (Ah+Al)[N,Kp] @ (Bh+Bl)^T, bf16x3, K-step 64 =====
#define GBM 64
#define GBN 128
#define GBK 64
__global__ __launch_bounds__(256) void k_gemm_bf3(
    const unsigned short* __restrict__ Ah, const unsigned short* __restrict__ Al,
    const unsigned short* __restrict__ Bh, const unsigned short* __restrict__ Bl,
    float* __restrict__ C, int N, int Kp, int M, int mode,
    const float* __restrict__ bias, unsigned short* __restrict__ outH,
    unsigned short* __restrict__ outL,
    const float* __restrict__ a_s, const float* __restrict__ a_d,
    float* __restrict__ as_o, float* __restrict__ ad_o, int Cdim){
  __shared__ unsigned short AsH[2*GBM*32], AsL[2*GBM*32];
  __shared__ unsigned short BsH[2*GBN*32], BsL[2*GBN*32];
  __shared__ float sred[2][GBM][4];
  int gx = M / GBN;
  int gy = (N + GBM - 1) / GBM;
  const int G = 8;
  int bid = blockIdx.x;
  int full = gy / G;
  int bid_full = full * G * gx;
  int by, bx;
  if (bid < bid_full){
    int g = bid / (G*gx); int rem = bid % (G*gx);
    by = g*G + rem % G; bx = rem / G;
  } else {
    int rem = bid - bid_full; int rows = gy - full*G;
    by = full*G + rem % rows; bx = rem / rows;
  }
  int row0 = by * GBM, col0 = bx * GBN;
  int t = threadIdx.x;
  int w = t >> 6, L = t & 63;
  int lm = L & 15, lq = L >> 4;
  int wc = w * 32;

  int sr = L >> 2, sc = L & 3;
  int art = w*16 + sr;
  int ga  = (sc - ((art >> 1) & 3)) & 3;
  int agrow = min(row0 + art, N-1);
  int brt0 = w*16 + sr;
  int brt1 = (w+4)*16 + sr;
  int gb0 = (sc - ((brt0 >> 1) & 3)) & 3;
  int gb1 = (sc - ((brt1 >> 1) & 3)) & 3;
  int bgrow0 = col0 + brt0, bgrow1 = col0 + brt1;

  int rc = (lq + (lm >> 1)) & 3;
  int aoff[4], boff[2];
#pragma unroll
  for (int mi = 0; mi < 4; mi++) aoff[mi] = (mi*16 + lm)*32 + rc*8;
#pragma unroll
  for (int ni = 0; ni < 2; ni++) boff[ni] = (wc + ni*16 + lm)*32 + rc*8;

  f32x4 acc[4][2];
#pragma unroll
  for (int i = 0; i < 4; i++)
#pragma unroll
    for (int j = 0; j < 2; j++) acc[i][j] = (f32x4){0.f,0.f,0.f,0.f};

  int nk = Kp / GBK;
  for (int kt = 0; kt < nk; kt++){
    int k0 = kt * GBK;
    if (kt) __syncthreads();
#pragma unroll
    for (int h = 0; h < 2; h++){
      int kh = k0 + h*32;
      gl_lds16(&Ah[(size_t)agrow*Kp + kh + ga*8],  &AsH[h*2048 + w*512]);
      gl_lds16(&Al[(size_t)agrow*Kp + kh + ga*8],  &AsL[h*2048 + w*512]);
      gl_lds16(&Bh[(size_t)bgrow0*Kp + kh + gb0*8], &BsH[h*4096 + w*512]);
      gl_lds16(&Bh[(size_t)bgrow1*Kp + kh + gb1*8], &BsH[h*4096 + (w+4)*512]);
      gl_lds16(&Bl[(size_t)bgrow0*Kp + kh + gb0*8], &BsL[h*4096 + w*512]);
      gl_lds16(&Bl[(size_t)bgrow1*Kp + kh + gb1*8], &BsL[h*4096 + (w+4)*512]);
    }
    __syncthreads();

#pragma unroll
    for (int h = 0; h < 2; h++){
      short8 ah[4], al[4], bh[2], bl[2];
#pragma unroll
      for (int mi = 0; mi < 4; mi++){
        ah[mi] = *(const short8*)&AsH[h*2048 + aoff[mi]];
        al[mi] = *(const short8*)&AsL[h*2048 + aoff[mi]];
      }
#pragma unroll
      for (int ni = 0; ni < 2; ni++){
        bh[ni] = *(const short8*)&BsH[h*4096 + boff[ni]];
        bl[ni] = *(const short8*)&BsL[h*4096 + boff[ni]];
      }
#pragma unroll
      for (int mi = 0; mi < 4; mi++)
#pragma unroll
        for (int ni = 0; ni < 2; ni++){
          acc[mi][ni] = __builtin_amdgcn_mfma_f32_16x16x32_bf16(ah[mi], bh[ni], acc[mi][ni], 0, 0, 0);
          acc[mi][ni] = __builtin_amdgcn_mfma_f32_16x16x32_bf16(ah[mi], bl[ni], acc[mi][ni], 0, 0, 0);
          acc[mi][ni] = __builtin_amdgcn_mfma_f32_16x16x32_bf16(al[mi], bh[ni], acc[mi][ni], 0, 0, 0);
        }
    }
  }
  if (mode == 1){
    // relu + bias; store H/L (GEMM2 A-operand) AND fp32 copy (gat residual read)
#pragma unroll
    for (int mi = 0; mi < 4; mi++)
#pragma unroll
      for (int ni = 0; ni < 2; ni++){
#pragma unroll
        for (int r = 0; r < 4; r++){
          int row = row0 + mi*16 + lq*4 + r;
          int col = col0 + wc + ni*16 + lm;
          if (row < N){
            float v = fmaxf(acc[mi][ni][r] + bias[col], 0.f);
            unsigned short hh, ll; split2(v, hh, ll);
            outH[(size_t)row*M + col] = hh;
            outL[(size_t)row*M + col] = ll;
            C[(size_t)row*M + col] = v;
          }
        }
      }
  } else if (mode != 3){
#pragma unroll
    for (int mi = 0; mi < 4; mi++)
#pragma unroll
      for (int ni = 0; ni < 2; ni++){
#pragma unroll
        for (int r = 0; r < 4; r++){
          int row = row0 + mi*16 + lq*4 + r;
          int col = col0 + wc + ni*16 + lm;
          if (row < N) C[(size_t)row*M + col] = acc[mi][ni][r];
        }
      }
  }
  if (mode == 2){
    float sA0 = a_s[col0 + wc + lm], sA1 = a_s[col0 + wc + 16 + lm];
    float dA0 = a_d[col0 + wc + lm], dA1 = a_d[col0 + wc + 16 + lm];
#pragma unroll
    for (int mi = 0; mi < 4; mi++)
#pragma unroll
      for (int r = 0; r < 4; r++){
        float vs = acc[mi][0][r]*sA0 + acc[mi][1][r]*sA1;
        float vd = acc[mi][0][r]*dA0 + acc[mi][1][r]*dA1;
#pragma unroll
        for (int o = 1; o <= 8; o <<= 1){
          vs += __shfl_xor(vs, o);
          vd += __shfl_xor(vd, o);
        }
        if (lm == 0){
          int row = mi*16 + lq*4 + r;
          sred[0][row][w] = vs;
          sred[1][row][w] = vd;
        }
      }
    __syncthreads();
    if (t < GBM){
      int n = row0 + t;
      if (n < N){
        int wph = Cdim >> 5;
        int nheads = 4 / wph;
        for (int g = 0; g < nheads; g++){
          float ss = 0.f, dd = 0.f;
          for (int q = 0; q < wph; q++){
            ss += sred[0][t][g*wph + q];
            dd += sred[1][t][g*wph + q];
          }
          int hd = (col0 + g*wph*32) / Cdim;
          as_o[n*NH + hd] = ss;
          ad_o[n*NH + hd] = dd;
        }
      }
    }
  } else if (mode == 3){
    float b0 = bias[col0 + wc + lm], b1v = bias[col0 + wc + 16 + lm];
    float w0v = a_s[col0 + wc + lm], w1v = a_s[col0 + wc + 16 + lm];
#pragma unroll
    for (int mi = 0; mi < 4; mi++)
#pragma unroll
      for (int r = 0; r < 4; r++){
        float v = tanhf(acc[mi][0][r] + b0)*w0v + tanhf(acc[mi][1][r] + b1v)*w1v;
#pragma unroll
        for (int o = 1; o <= 8; o <<= 1) v += __shfl_xor(v, o);
        if (lm == 0) sred[0][mi*16 + lq*4 + r][w] = v;
      }
    __syncthreads();
    if (t < GBM){
      int n = row0 + t;
      if (n < N){
        float s = sred[0][t][0] + sred[0][t][1] + sred[0][t][2] + sred[0][t][3];
        atomicAdd(&as_o[n], s);
      }
    }
  }
}

// ===== GCN pre-agg layer 0: fp32 x0 direct, 8-way, degree-sorted =====
__global__ __launch_bounds__(256) void k_gcn_pre0(
    const float* __restrict__ x0, const float* __restrict__ dinv,
    const int* __restrict__ rowptr, const int* __restrict__ colidx,
    const int* __restrict__ perm,
    unsigned short* __restrict__ outH, unsigned short* __restrict__ outL){
  int t = threadIdx.x;
  int sub = t & 15;
  int gid = blockIdx.x*16 + (t >> 4);
  if (gid >= NN) return;
  int n = perm[gid];
  int f0 = sub*4;
  bool act = f0 < 36;
  int b = rowptr[n], e = rowptr[n+1];
  float dn = dinv[n];
  float4 a0 = make_float4(0,0,0,0), a1 = make_float4(0,0,0,0);
  float4 a2 = make_float4(0,0,0,0), a3 = make_float4(0,0,0,0);
  if (act){
    float4 sv = *(const float4*)&x0[(size_t)n*36 + f0];
    int j = b;
    for (; j + 7 < e; j += 8){
      int s0 = colidx[j],   s1 = colidx[j+1], s2 = colidx[j+2], s3 = colidx[j+3];
      int s4 = colidx[j+4], s5 = colidx[j+5], s6 = colidx[j+6], s7 = colidx[j+7];
      float w0 = dinv[s0], w1 = dinv[s1], w2 = dinv[s2], w3 = dinv[s3];
      float w4 = dinv[s4], w5 = dinv[s5], w6 = dinv[s6], w7 = dinv[s7];
      float4 v0 = *(const float4*)&x0[(size_t)s0*36 + f0];
      float4 v1 = *(const float4*)&x0[(size_t)s1*36 + f0];
      float4 v2 = *(const float4*)&x0[(size_t)s2*36 + f0];
      float4 v3 = *(const float4*)&x0[(size_t)s3*36 + f0];
      float4 v4 = *(const float4*)&x0[(size_t)s4*36 + f0];
      float4 v5 = *(const float4*)&x0[(size_t)s5*36 + f0];
      float4 v6 = *(const float4*)&x0[(size_t)s6*36 + f0];
      float4 v7 = *(const float4*)&x0[(size_t)s7*36 + f0];
      fma4(a0, v0, w0*dn); fma4(a1, v1, w1*dn);
      fma4(a2, v2, w2*dn); fma4(a3, v3, w3*dn);
      fma4(a0, v4, w4*dn); fma4(a1, v5, w5*dn);
      fma4(a2, v6, w6*dn); fma4(a3, v7, w7*dn);
    }
    for (; j + 3 < e; j += 4){
      int s0 = colidx[j], s1 = colidx[j+1], s2 = colidx[j+2], s3 = colidx[j+3];
      float w0 = dinv[s0], w1 = dinv[s1], w2 = dinv[s2], w3 = dinv[s3];
      float4 v0 = *(const float4*)&x0[(size_t)s0*36 + f0];
      float4 v1 = *(const float4*)&x0[(size_t)s1*36 + f0];
      float4 v2 = *(const float4*)&x0[(size_t)s2*36 + f0];
      float4 v3 = *(const float4*)&x0[(size_t)s3*36 + f0];
      fma4(a0, v0, w0*dn); fma4(a1, v1, w1*dn);
      fma4(a2, v2, w2*dn); fma4(a3, v3, w3*dn);
    }
    for (; j < e; j++){
      int s = colidx[j];
      float4 v = *(const float4*)&x0[(size_t)s*36 + f0];
      fma4(a0, v, dinv[s]*dn);
    }
    float4 acc = make_float4(a0.x+a1.x+a2.x+a3.x, a0.y+a1.y+a2.y+a3.y,
                             a0.z+a1.z+a2.z+a3.z, a0.w+a1.w+a2.w+a3.w);
    float dn2 = dn*dn;
    acc.x += sv.x*dn2; acc.y += sv.y*dn2; acc.z += sv.z*dn2; acc.w += sv.w*dn2;
    store_hl(outH, outL, (size_t)n*64 + f0, acc);
  } else {
    store_hl(outH, outL, (size_t)n*64 + f0, make_float4(0,0,0,0));
  }
}

// ===== GCN pre-agg (layers 1..2): fp32 input (xf), 8-way, degree-sorted =====
__global__ __launch_bounds__(256) void k_gcn_pre(
    const float* __restrict__ xf, const float* __restrict__ dinv,
    const int* __restrict__ rowptr, const int* __restrict__ colidx,
    const int* __restrict__ perm,
    unsigned short* __restrict__ outH, unsigned short* __restrict__ outL,
    int Kp, int nchunk){
  int bid = blockIdx.x;
  int chunk = bid % nchunk, grp = bid / nchunk;
  int t = threadIdx.x;
  int sub = t & 15;
  int gid = grp*16 + (t >> 4);
  if (gid >= NN) return;
  int n = perm[gid];
  int f0 = chunk*64 + sub*4;
  int b = rowptr[n], e = rowptr[n+1];
  float dn = dinv[n];
  float4 sv = *(const float4*)&xf[(size_t)n*Kp + f0];
  float4 a0 = make_float4(0,0,0,0), a1 = make_float4(0,0,0,0);
  float4 a2 = make_float4(0,0,0,0), a3 = make_float4(0,0,0,0);
  int j = b;
  for (; j + 7 < e; j += 8){
    int s0 = colidx[j],   s1 = colidx[j+1], s2 = colidx[j+2], s3 = colidx[j+3];
    int s4 = colidx[j+4], s5 = colidx[j+5], s6 = colidx[j+6], s7 = colidx[j+7];
    float w0 = dinv[s0], w1 = dinv[s1], w2 = dinv[s2], w3 = dinv[s3];
    float w4 = dinv[s4], w5 = dinv[s5], w6 = dinv[s6], w7 = dinv[s7];
    float4 v0 = *(const float4*)&xf[(size_t)s0*Kp + f0];
    float4 v1 = *(const float4*)&xf[(size_t)s1*Kp + f0];
    float4 v2 = *(const float4*)&xf[(size_t)s2*Kp + f0];
    float4 v3 = *(const float4*)&xf[(size_t)s3*Kp + f0];
    float4 v4 = *(const float4*)&xf[(size_t)s4*Kp + f0];
    float4 v5 = *(const float4*)&xf[(size_t)s5*Kp + f0];
    float4 v6 = *(const float4*)&xf[(size_t)s6*Kp + f0];
    float4 v7 = *(const float4*)&xf[(size_t)s7*Kp + f0];
    fma4(a0, v0, w0*dn); fma4(a1, v1, w1*dn);
    fma4(a2, v2, w2*dn); fma4(a3, v3, w3*dn);
    fma4(a0, v4, w4*dn); fma4(a1, v5, w5*dn);
    fma4(a2, v6, w6*dn); fma4(a3, v7, w7*dn);
  }
  for (; j + 3 < e; j += 4){
    int s0 = colidx[j], s1 = colidx[j+1], s2 = colidx[j+2], s3 = colidx[j+3];
    float w0 = dinv[s0], w1 = dinv[s1], w2 = dinv[s2], w3 = dinv[s3];
    float4 v0 = *(const float4*)&xf[(size_t)s0*Kp + f0];
    float4 v1 = *(const float4*)&xf[(size_t)s1*Kp + f0];
    float4 v2 = *(const float4*)&xf[(size_t)s2*Kp + f0];
    float4 v3 = *(const float4*)&xf[(size_t)s3*Kp + f0];
    fma4(a0, v0, w0*dn); fma4(a1, v1, w1*dn);
    fma4(a2, v2, w2*dn); fma4(a3, v3, w3*dn);
  }
  for (; j < e; j++){
    int s = colidx[j];
    float4 v = *(const float4*)&xf[(size_t)s*Kp + f0];
    fma4(a0, v, dinv[s]*dn);
  }
  float4 acc = make_float4(a0.x+a1.x+a2.x+a3.x, a0.y+a1.y+a2.y+a3.y,
                           a0.z+a1.z+a2.z+a3.z, a0.w+a1.w+a2.w+a3.w);
  float dn2 = dn*dn;
  acc.x += sv.x*dn2; acc.y += sv.y*dn2; acc.z += sv.z*dn2; acc.w += sv.w*dn2;
  store_hl(outH, outL, (size_t)n*Kp + f0, acc);
}

// ===== GAT gather: fixed-shift softmax, fp32 residual, degree-sorted =====
__global__ __launch_bounds__(256) void k_gat_gather(
    const float* __restrict__ hg, const float* __restrict__ hf,
    const int* __restrict__ rowptr, const int* __restrict__ colidx,
    const int* __restrict__ perm,
    const float* __restrict__ as_, const float* __restrict__ ad_,
    const float* __restrict__ ab,
    unsigned short* __restrict__ outH, unsigned short* __restrict__ outL,
    float* __restrict__ xf,
    int M, int C, int nchunk){
  int bid = blockIdx.x;
  int chunk = bid % nchunk, grp = bid / nchunk;
  int t = threadIdx.x;
  int sub = t & 15;
  int gid = grp*16 + (t >> 4);
  if (gid >= NN) return;
  int n = perm[gid];
  int f0 = chunk*64 + sub*4;
  int hd = f0 / C;
  int b = rowptr[n], e = rowptr[n+1];
  int ai = n*NH + hd;
  float adn = ad_[ai];
  float sl = fminf(fmaxf(leakyf(as_[ai] + adn), -80.f), 80.f);
  float es = __expf(sl);
  // hoisted tail loads — latency hides under the edge loop
  float4 sv = *(const float4*)&hg[(size_t)n*M + f0];
  float4 hv = *(const float4*)&hf[(size_t)n*M + f0];
  float4 bb = *(const float4*)&ab[f0];
  float d = es;
  float4 a0 = make_float4(0,0,0,0), a1 = make_float4(0,0,0,0);
  float4 a2 = make_float4(0,0,0,0), a3 = make_float4(0,0,0,0);
  int j = b;
  for (; j + 7 < e; j += 8){
    int s0 = colidx[j],   s1 = colidx[j+1], s2 = colidx[j+2], s3 = colidx[j+3];
    int s4 = colidx[j+4], s5 = colidx[j+5], s6 = colidx[j+6], s7 = colidx[j+7];
    float l0 = leakyf(as_[s0*NH + hd] + adn), l1 = leakyf(as_[s1*NH + hd] + adn);
    float l2 = leakyf(as_[s2*NH + hd] + adn), l3 = leakyf(as_[s3*NH + hd] + adn);
    float l4 = leakyf(as_[s4*NH + hd] + adn), l5 = leakyf(as_[s5*NH + hd] + adn);
    float l6 = leakyf(as_[s6*NH + hd] + adn), l7 = leakyf(as_[s7*NH + hd] + adn);
    float4 v0 = *(const float4*)&hg[(size_t)s0*M + f0];
    float4 v1 = *(const float4*)&hg[(size_t)s1*M + f0];
    float4 v2 = *(const float4*)&hg[(size_t)s2*M + f0];
    float4 v3 = *(const float4*)&hg[(size_t)s3*M + f0];
    float4 v4 = *(const float4*)&hg[(size_t)s4*M + f0];
    float4 v5 = *(const float4*)&hg[(size_t)s5*M + f0];
    float4 v6 = *(const float4*)&hg[(size_t)s6*M + f0];
    float4 v7 = *(const float4*)&hg[(size_t)s7*M + f0];
    float w0 = __expf(fminf(fmaxf(l0,-80.f),80.f)), w1 = __expf(fminf(fmaxf(l1,-80.f),80.f));
    float w2 = __expf(fminf(fmaxf(l2,-80.f),80.f)), w3 = __expf(fminf(fmaxf(l3,-80.f),80.f));
    float w4 = __expf(fminf(fmaxf(l4,-80.f),80.f)), w5 = __expf(fminf(fmaxf(l5,-80.f),80.f));
    float w6 = __expf(fminf(fmaxf(l6,-80.f),80.f)), w7 = __expf(fminf(fmaxf(l7,-80.f),80.f));
    d += ((w0 + w1) + (w2 + w3)) + ((w4 + w5) + (w6 + w7));
    fma4(a0, v0, w0); fma4(a1, v1, w1);
    fma4(a2, v2, w2); fma4(a3, v3, w3);
    fma4(a0, v4, w4); fma4(a1, v5, w5);
    fma4(a2, v6, w6); fma4(a3, v7, w7);
  }
  for (; j < e; j++){
    int s = colidx[j];
    float l = leakyf(as_[s*NH + hd] + adn);
    float4 v = *(const float4*)&hg[(size_t)s*M + f0];
    float ww = __expf(fminf(fmaxf(l,-80.f),80.f));
    d += ww;
    fma4(a0, v, ww);
  }
  float4 acc = make_float4(a0.x+a1.x+a2.x+a3.x, a0.y+a1.y+a2.y+a3.y,
                           a0.z+a1.z+a2.z+a3.z, a0.w+a1.w+a2.w+a3.w);
  float inv = 1.f/d;
  float4 r = make_float4(
    hv.x + bb.x + (sv.x*es + acc.x)*inv,
    hv.y + bb.y + (sv.y*es + acc.y)*inv,
    hv.z + bb.z + (sv.z*es + acc.z)*inv,
    hv.w + bb.w + (sv.w*es + acc.w)*inv);
  *(float4*)&xf[(size_t)n*M + f0] = r;
  store_hl(outH, outL, (size_t)n*M + f0, r);
}

// ====== attention pooling: 2 blocks/graph (feature halves), 8-way node slice ======
__global__ __launch_bounds__(512) void k_pool(
    const float* __restrict__ xf,
    const float* __restrict__ apre, const int* __restrict__ starts,
    float* __restrict__ out){
  __shared__ float red[512];
  __shared__ float4 comb[3][8][64];   // 24 KB
  int g = blockIdx.x >> 1, half = blockIdx.x & 1;
  int t = threadIdx.x;
  int b = starts[g], e = starts[g+1];
  float m = -INFINITY;
  for (int n = b + t; n < e; n += 512) m = fmaxf(m, apre[n]);
  red[t] = m; __syncthreads();
  for (int o = 256; o > 0; o >>= 1){
    if (t < o) red[t] = fmaxf(red[t], red[t + o]);
    __syncthreads();
  }
  m = red[0]; __syncthreads();
  float s = 0.f;
  for (int n = b + t; n < e; n += 512) s += __expf(apre[n] - m);
  red[t] = s; __syncthreads();
  for (int o = 256; o > 0; o >>= 1){
    if (t < o) red[t] += red[t + o];
    __syncthreads();
  }
  float inv = 1.f / (red[0] + 1e-8f);
  int lf = t & 63, sl = t >> 6;          // 64 float4 feats × 8 node-slices
  int fo = half*64 + lf;                 // float4 index in [0,128)
  float4 sum = make_float4(0,0,0,0), wacc = make_float4(0,0,0,0);
  float4 mx = make_float4(-INFINITY,-INFINITY,-INFINITY,-INFINITY);
  for (int n = b + sl; n < e; n += 8){
    float4 xv = *(const float4*)&xf[(size_t)n*DOUT + fo*4];
    float p = __expf(apre[n] - m) * inv;
    sum.x += xv.x; sum.y += xv.y; sum.z += xv.z; sum.w += xv.w;
    mx.x = fmaxf(mx.x, xv.x); mx.y = fmaxf(mx.y, xv.y);
    mx.z = fmaxf(mx.z, xv.z); mx.w = fmaxf(mx.w, xv.w);
    fma4(wacc, xv, p);
  }
  comb[0][sl][lf] = wacc; comb[1][sl][lf] = sum; comb[2][sl][lf] = mx;
  __syncthreads();
  if (sl == 0){
#pragma unroll
    for (int q = 1; q < 8; q++){
      float4 w2 = comb[0][q][lf], s2 = comb[1][q][lf], m2 = comb[2][q][lf];
      wacc.x += w2.x; wacc.y += w2.y; wacc.z += w2.z; wacc.w += w2.w;
      sum.x += s2.x; sum.y += s2.y; sum.z += s2.z; sum.w += s2.w;
      mx.x = fmaxf(mx.x, m2.x); mx.y = fmaxf(mx.y, m2.y);
      mx.z = fmaxf(mx.z, m2.z); mx.w = fmaxf(mx.w, m2.w);
    }
    float ic = 1.f / fmaxf((float)(e - b), 1.f);
    float4* o = (float4*)(out + (size_t)g*4*DOUT);
    o[fo]       = wacc;
    o[128 + fo] = make_float4(sum.x*ic, sum.y*ic, sum.z*ic, sum.w*ic);
    o[256 + fo] = mx;
    o[384 + fo] = sum;
  }
}

extern "C" void kernel_launch(void* const* d_in, const int* in_sizes, int n_in,
                              void* d_out, int out_size, void* d_ws, size_t ws_size,
                              hipStream_t stream) {
  const float* x0   = (const float*)d_in[0];
  const int*   ei   = (const int*)d_in[1];
  const int*   src  = ei;
  const int*   dst  = ei + NE;
  const int*   batch= (const int*)d_in[2];
  const float* gw[3]  = {(const float*)d_in[3],  (const float*)d_in[9],  (const float*)d_in[15]};
  const float* gb[3]  = {(const float*)d_in[4],  (const float*)d_in[10], (const float*)d_in[16]};
  const float* aw[3]  = {(const float*)d_in[5],  (const float*)d_in[11], (const float*)d_in[17]};
  const float* asw[3] = {(const float*)d_in[6],  (const float*)d_in[12], (const float*)d_in[18]};
  const float* adw[3] = {(const float*)d_in[7],  (const float*)d_in[13], (const float*)d_in[19]};
  const float* ab[3]  = {(const float*)d_in[8],  (const float*)d_in[14], (const float*)d_in[20]};
  const float* apw1 = (const float*)d_in[21];
  const float* apb1 = (const float*)d_in[22];
  const float* apw2 = (const float*)d_in[23];
  float* out = (float*)d_out;

  // ---- workspace carve ----
  char* p = (char*)d_ws;
  auto alloc = [&](size_t bytes) -> void* {
    void* r = (void*)p; p += (bytes + 255) & ~(size_t)255; return r;
  };
  float* f1 = (float*)alloc((size_t)NN*512*4);            // hg (mode2 out, fp32)
  float* hf = (float*)alloc((size_t)NN*512*4);            // h  (mode1 out, fp32)
  float* xf = (float*)alloc((size_t)NN*512*4);            // gat out, fp32
  unsigned short* actH0 = (unsigned short*)alloc((size_t)NN*512*2);
  unsigned short* actL0 = (unsigned short*)alloc((size_t)NN*512*2);
  unsigned short* actH1 = (unsigned short*)alloc((size_t)NN*512*2);
  unsigned short* actL1 = (unsigned short*)alloc((size_t)NN*512*2);
  unsigned short* preH  = (unsigned short*)alloc((size_t)NN*256*2);
  unsigned short* preL  = (unsigned short*)alloc((size_t)NN*256*2);
  const int wK[7]  = {36, 128, 128, 256, 256, 512, 512};
  const int wM[7]  = {128, 128, 256, 256, 512, 512, 256};
  const int wKp[7] = {64, 128, 128, 256, 256, 512, 512};
  const float* wsrc[7] = {gw[0], aw[0], gw[1], aw[1], gw[2], aw[2], apw1};
  unsigned short* wTh[7]; unsigned short* wTl[7];
  for (int i = 0; i < 7; i++){
    size_t sz = (size_t)wM[i]*wKp[i]*2;
    wTh[i] = (unsigned short*)alloc(sz);
    wTl[i] = (unsigned short*)alloc(sz);
  }
  float* dinv = (float*)alloc(NN*4);
  float* as_  = (float*)alloc(NN*NH*4);
  float* ad_  = (float*)alloc(NN*NH*4);
  float* apre = (float*)alloc(NN*4);
  int* rowptr = (int*)alloc((NN+1)*4);
  int* colidx = (int*)alloc((size_t)NE*4);
  int* cnt    = (int*)alloc(NN*4);
  int* cursor = (int*)alloc(NN*4);
  int* starts = (int*)alloc((NB+1)*4);
  int* perm   = (int*)alloc(NN*4);

  // ---- conv descriptor (weights only) ----
  AllConv ac;
  int convTot = 0;
  for (int i = 0; i < 7; i++){
    ac.src[i] = wsrc[i]; ac.dh[i] = wTh[i]; ac.dl[i] = wTl[i];
    ac.K[i] = wK[i]; ac.Mm[i] = wM[i]; ac.Kp[i] = wKp[i];
    ac.tot[i] = wKp[i]*wM[i];
    convTot += ac.tot[i];
  }

  // ---- CSR build (count merged with conversions) -> single-block scan -> fill ----
  hipMemsetAsync(cnt, 0, NN*sizeof(int), stream);
  int convBlks = (convTot + 255) / 256;
  k_count_conv<<<CNT_BLKS + convBlks, 256, 0, stream>>>(dst, cnt, ac, convTot);
  k_scan_all<<<1, 1024, 0, stream>>>(cnt, batch, rowptr, dinv, cursor, apre, starts, perm);
  k_fill<<<(NE+255)/256, 256, 0, stream>>>(src, dst, rowptr, cursor, colidx);

  const int dims[4] = {36, 128, 256, 512};
  const int ngrp = (NN + 15) / 16;
  int wi = 0;
  for (int i = 0; i < 3; i++){
    int Kin = (i == 0) ? 64 : dims[i];
    int M = dims[i+1], C = M/NH;
    int nchunk_in = Kin / 64;
    int nchunk = M / 64;
    int nblk = (M/GBN) * ((NN+GBM-1)/GBM);
    if (i == 0){
      k_gcn_pre0<<<ngrp, 256, 0, stream>>>(x0, dinv, rowptr, colidx, perm, preH, preL);
    } else {
      k_gcn_pre<<<nchunk_in*ngrp, 256, 0, stream>>>(xf, dinv, rowptr, colidx, perm,
                                                    preH, preL, Kin, nchunk_in);
    }
    k_gemm_bf3<<<nblk, 256, 0, stream>>>(preH, preL, wTh[wi], wTl[wi], hf, NN, wKp[wi], M,
                                         1, gb[i], actH0, actL0,
                                         nullptr, nullptr, nullptr, nullptr, C);
    wi++;
    k_gemm_bf3<<<nblk, 256, 0, stream>>>(actH0, actL0, wTh[wi], wTl[wi], f1, NN, wKp[wi], M,
                                         2, nullptr, nullptr, nullptr,
                                         asw[i], adw[i], as_, ad_, C);
    wi++;
    k_gat_gather<<<nchunk*ngrp, 256, 0, stream>>>(f1, hf, rowptr, colidx, perm,
                                                  as_, ad_, ab[i],
                                                  actH1, actL1, xf, M, C, nchunk);
  }

  // ---- pooling ----
  {
    int nblk = (256/GBN) * ((NN+GBM-1)/GBM);
    k_gemm_bf3<<<nblk, 256, 0, stream>>>(actH1, actL1, wTh[6], wTl[6], nullptr, NN, wKp[6], 256,
                                         3, apb1, nullptr, nullptr,
                                         apw2, nullptr, apre, nullptr, 64);
  }
  k_pool<<<NB*2, 512, 0, stream>>>(xf, apre, starts, out);
}